// Round 3
// baseline (605.737 us; speedup 1.0000x reference)
//
#include <hip/hip_runtime.h>
#include <hip/hip_bf16.h>

// SlotAttention: B=32, N=16384, D=64, S=7, H=128, 3 iterations.
//   proj_kernel : LN(inputs) -> k,v bf16 (MFMA, A=weights so lanes own 4 consecutive feats)
//   init_kernel : slots0, h0, zero acc, q0
//   3x { attn_kernel : softmax over S, dual-norm commuted into W/C accumulators
//        slot_update : W/C -> GRU -> MLP -> slots -> next q }

#define B_ 32
#define N_ 16384
#define D_ 64
#define S_ 7

typedef __bf16 bf16x8 __attribute__((ext_vector_type(8)));
typedef float floatx4 __attribute__((ext_vector_type(4)));

__device__ __forceinline__ unsigned int f2bfu(float f) {
  __hip_bfloat16 h = __float2bfloat16(f);
  return (unsigned int)__builtin_bit_cast(unsigned short, h);
}
__device__ __forceinline__ unsigned int pack2bf(float lo, float hi) {
  return f2bfu(lo) | (f2bfu(hi) << 16);
}
__device__ __forceinline__ float bf2f(unsigned short u) {
  return __uint_as_float(((unsigned int)u) << 16);
}

// ---------------- proj: LN + K/V projection (bf16 MFMA) ----------------
// s_xn layout: row r (128), 8 chunks of 16B; chunk c stored at slot c^(r&7) (bank-even)
__global__ __launch_bounds__(256) void proj_kernel(
    const float* __restrict__ x,
    const float* __restrict__ lng, const float* __restrict__ lnb,
    const float* __restrict__ Wk, const float* __restrict__ Wv,
    unsigned short* __restrict__ kb, unsigned short* __restrict__ vb)
{
  __shared__ __align__(16) unsigned short s_xn[128 * 64];
  __shared__ __align__(16) unsigned short s_w[128 * 64];  // [feat][d]; feat<64: Wk, else Wv
  const int t = threadIdx.x;
  const int lane = t & 63;
  const int w = t >> 6;
  const int R0 = blockIdx.x * 128;

  // ---- stage weights, vectorized: 8192 f32 -> bf16 ----
  for (int j = 0; j < 2; ++j) {
    int idx = (t + j * 256) * 16;  // 16 consecutive elems
    const float* src = (idx < 4096) ? (Wk + idx) : (Wv + idx - 4096);
    float4 a = ((const float4*)src)[0], b = ((const float4*)src)[1];
    float4 c = ((const float4*)src)[2], d = ((const float4*)src)[3];
    uint4 p0, p1;
    p0.x = pack2bf(a.x, a.y); p0.y = pack2bf(a.z, a.w);
    p0.z = pack2bf(b.x, b.y); p0.w = pack2bf(b.z, b.w);
    p1.x = pack2bf(c.x, c.y); p1.y = pack2bf(c.z, c.w);
    p1.z = pack2bf(d.x, d.y); p1.w = pack2bf(d.z, d.w);
    ((uint4*)s_w)[idx >> 3] = p0;
    ((uint4*)s_w)[(idx >> 3) + 1] = p1;
  }

  // ---- LayerNorm: 4 lanes per row, 16 f32 each, 2-level shuffle ----
  const int ql = t & 3;
  float4 g4[4], b4[4];
#pragma unroll
  for (int j = 0; j < 4; ++j) {
    g4[j] = *(const float4*)&lng[ql * 16 + j * 4];
    b4[j] = *(const float4*)&lnb[ql * 16 + j * 4];
  }
#pragma unroll
  for (int half = 0; half < 2; ++half) {
    int r = half * 64 + (t >> 2);
    const float4* xp = (const float4*)&x[(size_t)(R0 + r) * 64 + ql * 16];
    float4 xv[4];
#pragma unroll
    for (int j = 0; j < 4; ++j) xv[j] = xp[j];
    float s1 = 0.f, s2 = 0.f;
#pragma unroll
    for (int j = 0; j < 4; ++j) {
      s1 += xv[j].x + xv[j].y + xv[j].z + xv[j].w;
      s2 += xv[j].x * xv[j].x + xv[j].y * xv[j].y + xv[j].z * xv[j].z + xv[j].w * xv[j].w;
    }
    s1 += __shfl_xor(s1, 1); s2 += __shfl_xor(s2, 1);
    s1 += __shfl_xor(s1, 2); s2 += __shfl_xor(s2, 2);
    float mean = s1 * 0.015625f;
    float var = s2 * 0.015625f - mean * mean;
    float rs = rsqrtf(var + 1e-5f);
    float y[16];
#pragma unroll
    for (int j = 0; j < 4; ++j) {
      y[j * 4 + 0] = (xv[j].x - mean) * rs * g4[j].x + b4[j].x;
      y[j * 4 + 1] = (xv[j].y - mean) * rs * g4[j].y + b4[j].y;
      y[j * 4 + 2] = (xv[j].z - mean) * rs * g4[j].z + b4[j].z;
      y[j * 4 + 3] = (xv[j].w - mean) * rs * g4[j].w + b4[j].w;
    }
#pragma unroll
    for (int h = 0; h < 2; ++h) {
      uint4 p;
      p.x = pack2bf(y[h * 8 + 0], y[h * 8 + 1]);
      p.y = pack2bf(y[h * 8 + 2], y[h * 8 + 3]);
      p.z = pack2bf(y[h * 8 + 4], y[h * 8 + 5]);
      p.w = pack2bf(y[h * 8 + 6], y[h * 8 + 7]);
      int c = ql * 2 + h;
      int sc = c ^ (r & 7);
      *(uint4*)&s_xn[r * 64 + sc * 8] = p;
    }
  }
  __syncthreads();

  // ---- MFMA: A = W (m=feat), B = xn (n=xrow); D row=feat(quad*4+rg), col=xrow ----
  const int m16 = lane & 15, quad = lane >> 4;
  bf16x8 bf[2][2];
#pragma unroll
  for (int nt = 0; nt < 2; ++nt) {
    int xr = (w * 2 + nt) * 16 + m16;
#pragma unroll
    for (int kt = 0; kt < 2; ++kt)
      bf[nt][kt] = *(const bf16x8*)&s_xn[xr * 64 + (((kt * 4 + quad) ^ (xr & 7)) * 8)];
  }
#pragma unroll
  for (int mt = 0; mt < 8; ++mt) {
    bf16x8 a0 = *(const bf16x8*)&s_w[(mt * 16 + m16) * 64 + quad * 8];
    bf16x8 a1 = *(const bf16x8*)&s_w[(mt * 16 + m16) * 64 + 32 + quad * 8];
#pragma unroll
    for (int nt = 0; nt < 2; ++nt) {
      floatx4 acc = (floatx4){0.f, 0.f, 0.f, 0.f};
      acc = __builtin_amdgcn_mfma_f32_16x16x32_bf16(a0, bf[nt][0], acc, 0, 0, 0);
      acc = __builtin_amdgcn_mfma_f32_16x16x32_bf16(a1, bf[nt][1], acc, 0, 0, 0);
      int xrow_g = R0 + (w * 2 + nt) * 16 + m16;
      int col = (mt & 3) * 16 + quad * 4;  // 4 consecutive feats per lane
      uint2 p;
      p.x = pack2bf(acc[0], acc[1]);
      p.y = pack2bf(acc[2], acc[3]);
      unsigned short* dst = (mt < 4) ? kb : vb;
      *(uint2*)&dst[(size_t)xrow_g * 64 + col] = p;
    }
  }
}

// ---------------- shared helper: q = LN(slots; ln_slots) @ Wq^T * scale ----------------
__device__ void q_from_slots(const float* s_slot, float* s_tmp,
                             const float* __restrict__ g, const float* __restrict__ bb,
                             const float* __restrict__ Wq, float* __restrict__ qout,
                             int lane, int w)
{
  for (int ss = 0; ss < 2; ++ss) {
    int srow = ss * 4 + w;
    if (srow < 7) {
      float xv = s_slot[srow * 64 + lane];
      float s1 = xv, s2 = xv * xv;
#pragma unroll
      for (int mm = 1; mm < 64; mm <<= 1) {
        s1 += __shfl_xor(s1, mm);
        s2 += __shfl_xor(s2, mm);
      }
      float mean = s1 * 0.015625f;
      float var = s2 * 0.015625f - mean * mean;
      float rs = rsqrtf(var + 1e-5f);
      s_tmp[w * 64 + lane] = (xv - mean) * rs * g[lane] + bb[lane];
    }
    __syncthreads();
    if (srow < 7) {
      float acc = 0.f;
      const float* wr = Wq + lane * 64;
      const float* xr = s_tmp + w * 64;
      for (int d = 0; d < 64; ++d) acc += xr[d] * wr[d];
      qout[srow * 64 + lane] = acc * 0.125f;
    }
    __syncthreads();
  }
}

// ---------------- init ----------------
__global__ __launch_bounds__(256) void init_kernel(
    const float* __restrict__ mu, const float* __restrict__ lsig,
    const float* __restrict__ nslots, const float* __restrict__ nh,
    const float* __restrict__ ln_s_g, const float* __restrict__ ln_s_b,
    const float* __restrict__ Wq,
    float* __restrict__ qbuf, float* __restrict__ Wacc, float* __restrict__ Cacc,
    float* __restrict__ h0b)
{
  __shared__ float s_slot[448];
  __shared__ float s_tmp[256];
  const int b = blockIdx.x, t = threadIdx.x, lane = t & 63, w = t >> 6;
  for (int o = t; o < 448; o += 256) {
    int d = o & 63;
    s_slot[o] = mu[d] + expf(lsig[d]) * nslots[b * 448 + o];
    Wacc[b * 448 + o] = 0.f;
  }
  if (t < 64) h0b[b * 64 + t] = mu[t] + expf(lsig[t]) * nh[b * 64 + t];
  if (t < 8) Cacc[b * 8 + t] = 0.f;
  __syncthreads();
  q_from_slots(s_slot, s_tmp, ln_s_g, ln_s_b, Wq, qbuf + b * 448, lane, w);
}

// ---------------- attention pass ----------------
// grid (32, 32): block = 512 rows of one b; wave = 128 rows = 2 tiles of 64.
// All per-tile LDS (s_k, s_attn) is wave-private -> NO per-tile __syncthreads.
__global__ __launch_bounds__(256) void attn_kernel(
    const unsigned short* __restrict__ kb, const unsigned short* __restrict__ vb,
    const float* __restrict__ qbuf,
    float* __restrict__ Wacc, float* __restrict__ Cacc)
{
  __shared__ __align__(16) unsigned short s_k[4][64 * 64];  // xor-swizzled per-wave tile
  __shared__ __align__(16) float s_attn[4][64 * 12];
  __shared__ __align__(16) float s_red[4][7 * 64];
  __shared__ float s_cred[4][8];
  __shared__ __align__(16) float s_q[448];

  const int b = blockIdx.y;
  const int t = threadIdx.x, lane = t & 63, w = t >> 6;
  const int lo3 = lane & 7, hi3 = lane >> 3;

  for (int i = t; i < 448; i += 256) s_q[i] = qbuf[b * 448 + i];
  __syncthreads();

  float accs[7][8];
#pragma unroll
  for (int s = 0; s < 7; ++s)
#pragma unroll
    for (int dj = 0; dj < 8; ++dj) accs[s][dj] = 0.f;
  float cloc[7];
#pragma unroll
  for (int s = 0; s < 7; ++s) cloc[s] = 0.f;

  const int rowbase = b * N_ + blockIdx.x * 512 + w * 128;

  for (int tile = 0; tile < 2; ++tile) {
    const int r0 = rowbase + tile * 64;
    // stage k (16B chunks, chunk slot = c ^ (row&7))
#pragma unroll
    for (int i = 0; i < 8; ++i) {
      int rr = i * 8 + hi3;
      int gc = lo3 ^ (rr & 7);
      uint4 d4 = *(const uint4*)&kb[(size_t)(r0 + rr) * 64 + gc * 8];
      *(uint4*)&s_k[w][rr * 64 + lo3 * 8] = d4;
    }
    // phase 1: lane = row
    float lg[7];
#pragma unroll
    for (int s = 0; s < 7; ++s) lg[s] = 0.f;
#pragma unroll
    for (int c = 0; c < 8; ++c) {
      int slot = c ^ (lane & 7);
      uint4 kk = *(const uint4*)&s_k[w][lane * 64 + slot * 8];
      float kf[8];
      kf[0] = __uint_as_float(kk.x << 16);
      kf[1] = __uint_as_float(kk.x & 0xffff0000u);
      kf[2] = __uint_as_float(kk.y << 16);
      kf[3] = __uint_as_float(kk.y & 0xffff0000u);
      kf[4] = __uint_as_float(kk.z << 16);
      kf[5] = __uint_as_float(kk.z & 0xffff0000u);
      kf[6] = __uint_as_float(kk.w << 16);
      kf[7] = __uint_as_float(kk.w & 0xffff0000u);
#pragma unroll
      for (int s = 0; s < 7; ++s) {
        const float* qp = s_q + s * 64 + c * 8;
        float a = lg[s];
#pragma unroll
        for (int j = 0; j < 8; ++j) a += kf[j] * qp[j];
        lg[s] = a;
      }
    }
    float mx = lg[0];
#pragma unroll
    for (int s = 1; s < 7; ++s) mx = fmaxf(mx, lg[s]);
    float ex[7]; float sum = 0.f;
#pragma unroll
    for (int s = 0; s < 7; ++s) { ex[s] = __expf(lg[s] - mx); sum += ex[s]; }
    float inv = 1.f / sum;
    float at[7];
#pragma unroll
    for (int s = 0; s < 7; ++s) { at[s] = ex[s] * inv + 1e-8f; cloc[s] += at[s]; }
    float4 w0 = {at[0], at[1], at[2], at[3]};
    float4 w1 = {at[4], at[5], at[6], 0.f};
    *(float4*)&s_attn[w][lane * 12] = w0;
    *(float4*)&s_attn[w][lane * 12 + 4] = w1;
    // phase 2: lane = (r-octet hi3, d-octet lo3); v read direct from global, 16B coalesced
#pragma unroll
    for (int rr = 0; rr < 8; ++rr) {
      int r = rr * 8 + hi3;
      uint4 vv = *(const uint4*)&vb[(size_t)(r0 + r) * 64 + lo3 * 8];
      float vf[8];
      vf[0] = __uint_as_float(vv.x << 16);
      vf[1] = __uint_as_float(vv.x & 0xffff0000u);
      vf[2] = __uint_as_float(vv.y << 16);
      vf[3] = __uint_as_float(vv.y & 0xffff0000u);
      vf[4] = __uint_as_float(vv.z << 16);
      vf[5] = __uint_as_float(vv.z & 0xffff0000u);
      vf[6] = __uint_as_float(vv.w << 16);
      vf[7] = __uint_as_float(vv.w & 0xffff0000u);
      float4 a0 = *(const float4*)&s_attn[w][r * 12];
      float4 a1 = *(const float4*)&s_attn[w][r * 12 + 4];
      float av[7] = {a0.x, a0.y, a0.z, a0.w, a1.x, a1.y, a1.z};
#pragma unroll
      for (int s = 0; s < 7; ++s)
#pragma unroll
        for (int dj = 0; dj < 8; ++dj) accs[s][dj] += av[s] * vf[dj];
    }
  }
  // reduce accs over hi3 (xor 8/16/32)
#pragma unroll
  for (int s = 0; s < 7; ++s)
#pragma unroll
    for (int dj = 0; dj < 8; ++dj) {
      float v = accs[s][dj];
      v += __shfl_xor(v, 8);
      v += __shfl_xor(v, 16);
      v += __shfl_xor(v, 32);
      accs[s][dj] = v;
    }
  if (hi3 == 0) {
#pragma unroll
    for (int s = 0; s < 7; ++s)
#pragma unroll
      for (int dj = 0; dj < 8; ++dj)
        s_red[w][s * 64 + lo3 * 8 + dj] = accs[s][dj];
  }
  // reduce cloc across all 64 lanes
#pragma unroll
  for (int s = 0; s < 7; ++s) {
    float c = cloc[s];
#pragma unroll
    for (int mm = 1; mm < 64; mm <<= 1) c += __shfl_xor(c, mm);
    cloc[s] = c;
  }
  if (lane == 0) {
#pragma unroll
    for (int s = 0; s < 7; ++s) s_cred[w][s] = cloc[s];
  }
  __syncthreads();
  if (w == 0) {
#pragma unroll
    for (int s = 0; s < 7; ++s) {
      float v = s_red[0][s * 64 + lane] + s_red[1][s * 64 + lane] +
                s_red[2][s * 64 + lane] + s_red[3][s * 64 + lane];
      atomicAdd(&Wacc[b * 448 + s * 64 + lane], v);
    }
    if (lane < 7) {
      float c = s_cred[0][lane] + s_cred[1][lane] + s_cred[2][lane] + s_cred[3][lane];
      atomicAdd(&Cacc[b * 8 + lane], c);
    }
  }
}

// ---------------- slot update ----------------
__global__ __launch_bounds__(256) void slot_update_kernel(
    float* __restrict__ Wacc, float* __restrict__ Cacc,
    const float* __restrict__ h0b,
    const float* __restrict__ w_ih, const float* __restrict__ w_hh,
    const float* __restrict__ b_ih, const float* __restrict__ b_hh,
    const float* __restrict__ ln_m_g, const float* __restrict__ ln_m_b,
    const float* __restrict__ w1, const float* __restrict__ b1,
    const float* __restrict__ w2, const float* __restrict__ b2,
    const float* __restrict__ ln_s_g, const float* __restrict__ ln_s_b,
    const float* __restrict__ Wq,
    float* __restrict__ qbuf, float* __restrict__ out)
{
  const int b = blockIdx.x, t = threadIdx.x, lane = t & 63, w = t >> 6;
  __shared__ float s_upd[448];
  __shared__ float s_gi[1344];
  __shared__ float s_h[64];
  __shared__ float s_gh[192];
  __shared__ float s_slot[448];
  __shared__ float s_tmp[256];

  for (int o = t; o < 448; o += 256) {
    int s = o >> 6;
    s_upd[o] = Wacc[b * 448 + o] / Cacc[b * 8 + s];
  }
  __syncthreads();
  for (int o = t; o < 1344; o += 256) {
    int s = o / 192, j = o - s * 192;
    float acc = b_ih[j];
    const float* wr = w_ih + j * 64;
    const float* ur = s_upd + s * 64;
    for (int d = 0; d < 64; ++d) acc += ur[d] * wr[d];
    s_gi[o] = acc;
  }
  if (t < 64) s_h[t] = h0b[b * 64 + t];
  __syncthreads();
  for (int s = 0; s < 7; ++s) {
    if (t < 192) {
      float acc = b_hh[t];
      const float* wr = w_hh + t * 64;
      for (int d = 0; d < 64; ++d) acc += s_h[d] * wr[d];
      s_gh[t] = acc;
    }
    __syncthreads();
    if (t < 64) {
      float ir = s_gi[s * 192 + t], iz = s_gi[s * 192 + 64 + t], inn = s_gi[s * 192 + 128 + t];
      float hr = s_gh[t], hz = s_gh[64 + t], hn = s_gh[128 + t];
      float r = 1.f / (1.f + expf(-(ir + hr)));
      float z = 1.f / (1.f + expf(-(iz + hz)));
      float n = tanhf(inn + r * hn);
      float hnew = (1.f - z) * n + z * s_h[t];
      s_slot[s * 64 + t] = hnew;
      s_h[t] = hnew;
    }
    __syncthreads();
  }
  float* s_sn = s_gi;
  float* s_hid = s_gi + 448;
  for (int ss = 0; ss < 2; ++ss) {
    int srow = ss * 4 + w;
    if (srow < 7) {
      float xv = s_slot[srow * 64 + lane];
      float s1 = xv, s2 = xv * xv;
#pragma unroll
      for (int mm = 1; mm < 64; mm <<= 1) {
        s1 += __shfl_xor(s1, mm);
        s2 += __shfl_xor(s2, mm);
      }
      float mean = s1 * 0.015625f;
      float var = s2 * 0.015625f - mean * mean;
      float rs = rsqrtf(var + 1e-5f);
      s_sn[srow * 64 + lane] = (xv - mean) * rs * ln_m_g[lane] + ln_m_b[lane];
    }
  }
  __syncthreads();
  for (int o = t; o < 896; o += 256) {
    int s = o >> 7, hh = o & 127;
    float acc = b1[hh];
    const float* wr = w1 + hh * 64;
    const float* xr = s_sn + s * 64;
    for (int d = 0; d < 64; ++d) acc += xr[d] * wr[d];
    s_hid[o] = fmaxf(acc, 0.f);
  }
  __syncthreads();
  for (int o = t; o < 448; o += 256) {
    int s = o >> 6, d = o & 63;
    float acc = b2[d];
    const float* wr = w2 + d * 128;
    const float* hr = s_hid + s * 128;
    for (int h = 0; h < 128; ++h) acc += hr[h] * wr[h];
    float val = s_slot[o] + acc;
    s_slot[o] = val;
    out[b * 448 + o] = val;
  }
  for (int o = t; o < 448; o += 256) Wacc[b * 448 + o] = 0.f;
  if (t < 8) Cacc[b * 8 + t] = 0.f;
  __syncthreads();
  q_from_slots(s_slot, s_tmp, ln_s_g, ln_s_b, Wq, qbuf + b * 448, lane, w);
}

extern "C" void kernel_launch(void* const* d_in, const int* in_sizes, int n_in,
                              void* d_out, int out_size, void* d_ws, size_t ws_size,
                              hipStream_t stream)
{
  (void)in_sizes; (void)n_in; (void)out_size; (void)ws_size;
  const float* x      = (const float*)d_in[0];
  const float* ln_in_g = (const float*)d_in[1];
  const float* ln_in_b = (const float*)d_in[2];
  const float* ln_s_g  = (const float*)d_in[3];
  const float* ln_s_b  = (const float*)d_in[4];
  const float* ln_m_g  = (const float*)d_in[5];
  const float* ln_m_b  = (const float*)d_in[6];
  const float* Wq = (const float*)d_in[7];
  const float* Wk = (const float*)d_in[8];
  const float* Wv = (const float*)d_in[9];
  const float* mu = (const float*)d_in[10];
  const float* lsig = (const float*)d_in[11];
  const float* w_ih = (const float*)d_in[12];
  const float* w_hh = (const float*)d_in[13];
  const float* b_ih = (const float*)d_in[14];
  const float* b_hh = (const float*)d_in[15];
  const float* w1 = (const float*)d_in[16];
  const float* b1 = (const float*)d_in[17];
  const float* w2 = (const float*)d_in[18];
  const float* b2 = (const float*)d_in[19];
  const float* nslots = (const float*)d_in[20];
  const float* nh = (const float*)d_in[21];

  unsigned short* kb = (unsigned short*)d_ws;
  unsigned short* vb = kb + (size_t)B_ * N_ * D_;
  float* fb = (float*)(vb + (size_t)B_ * N_ * D_);
  float* qbuf = fb;            // 32*448
  float* Wacc = fb + 14336;    // 32*448
  float* Cacc = fb + 28672;    // 32*8
  float* h0b  = fb + 28928;    // 32*64
  float* out = (float*)d_out;

  proj_kernel<<<4096, 256, 0, stream>>>(x, ln_in_g, ln_in_b, Wk, Wv, kb, vb);
  init_kernel<<<32, 256, 0, stream>>>(mu, lsig, nslots, nh, ln_s_g, ln_s_b, Wq,
                                      qbuf, Wacc, Cacc, h0b);
  for (int it = 0; it < 3; ++it) {
    attn_kernel<<<dim3(32, 32), 256, 0, stream>>>(kb, vb, qbuf, Wacc, Cacc);
    slot_update_kernel<<<32, 256, 0, stream>>>(Wacc, Cacc, h0b, w_ih, w_hh, b_ih, b_hh,
                                               ln_m_g, ln_m_b, w1, b1, w2, b2,
                                               ln_s_g, ln_s_b, Wq, qbuf, out);
  }
}

// Round 4
// 488.773 us; speedup vs baseline: 1.2393x; 1.2393x over previous
//
#include <hip/hip_runtime.h>
#include <hip/hip_bf16.h>

// SlotAttention: B=32, N=16384, D=64, S=7, H=128, 3 iterations.
//   proj_kernel : LN(inputs) -> kT[b][d][n] (transposed, bf16) + v[b][n][d] (bf16) via MFMA
//   init_kernel : slots0, h0, zero acc, q0
//   3x { attn_kernel : in-register softmax over S, dual-norm commuted into W/C accumulators
//        slot_update : W/C -> GRU -> MLP -> slots -> next q }

#define B_ 32
#define N_ 16384
#define D_ 64
#define S_ 7

typedef __bf16 bf16x8 __attribute__((ext_vector_type(8)));
typedef float floatx4 __attribute__((ext_vector_type(4)));

__device__ __forceinline__ unsigned int f2bfu(float f) {
  __hip_bfloat16 h = __float2bfloat16(f);
  return (unsigned int)__builtin_bit_cast(unsigned short, h);
}
__device__ __forceinline__ unsigned int pack2bf(float lo, float hi) {
  return f2bfu(lo) | (f2bfu(hi) << 16);
}

// ---------------- proj: LN + K/V projection (bf16 MFMA) ----------------
// k stored TRANSPOSED: kT[b][d][n]  (attn phase-1 reads columns of n coalesced)
// v stored row-major:  v[b][n][d]
__global__ __launch_bounds__(256) void proj_kernel(
    const float* __restrict__ x,
    const float* __restrict__ lng, const float* __restrict__ lnb,
    const float* __restrict__ Wk, const float* __restrict__ Wv,
    unsigned short* __restrict__ kt, unsigned short* __restrict__ vb)
{
  __shared__ __align__(16) unsigned short s_xn[128 * 64];
  __shared__ __align__(16) unsigned short s_w[128 * 64];  // [feat][d]; feat<64: Wk, else Wv
  const int t = threadIdx.x;
  const int lane = t & 63;
  const int w = t >> 6;
  const int R0 = blockIdx.x * 128;
  const int bb = R0 >> 14;          // batch index (N_=16384 rows per b)
  const int nbase = R0 & (N_ - 1);  // n offset within b

  // ---- stage weights, vectorized: 8192 f32 -> bf16 ----
  for (int j = 0; j < 2; ++j) {
    int idx = (t + j * 256) * 16;
    const float* src = (idx < 4096) ? (Wk + idx) : (Wv + idx - 4096);
    float4 a = ((const float4*)src)[0], b = ((const float4*)src)[1];
    float4 c = ((const float4*)src)[2], d = ((const float4*)src)[3];
    uint4 p0, p1;
    p0.x = pack2bf(a.x, a.y); p0.y = pack2bf(a.z, a.w);
    p0.z = pack2bf(b.x, b.y); p0.w = pack2bf(b.z, b.w);
    p1.x = pack2bf(c.x, c.y); p1.y = pack2bf(c.z, c.w);
    p1.z = pack2bf(d.x, d.y); p1.w = pack2bf(d.z, d.w);
    ((uint4*)s_w)[idx >> 3] = p0;
    ((uint4*)s_w)[(idx >> 3) + 1] = p1;
  }

  // ---- LayerNorm: 4 lanes per row, 16 f32 each, 2-level shuffle ----
  const int ql = t & 3;
  float4 g4[4], b4[4];
#pragma unroll
  for (int j = 0; j < 4; ++j) {
    g4[j] = *(const float4*)&lng[ql * 16 + j * 4];
    b4[j] = *(const float4*)&lnb[ql * 16 + j * 4];
  }
#pragma unroll
  for (int half = 0; half < 2; ++half) {
    int r = half * 64 + (t >> 2);
    const float4* xp = (const float4*)&x[(size_t)(R0 + r) * 64 + ql * 16];
    float4 xv[4];
#pragma unroll
    for (int j = 0; j < 4; ++j) xv[j] = xp[j];
    float s1 = 0.f, s2 = 0.f;
#pragma unroll
    for (int j = 0; j < 4; ++j) {
      s1 += xv[j].x + xv[j].y + xv[j].z + xv[j].w;
      s2 += xv[j].x * xv[j].x + xv[j].y * xv[j].y + xv[j].z * xv[j].z + xv[j].w * xv[j].w;
    }
    s1 += __shfl_xor(s1, 1); s2 += __shfl_xor(s2, 1);
    s1 += __shfl_xor(s1, 2); s2 += __shfl_xor(s2, 2);
    float mean = s1 * 0.015625f;
    float var = s2 * 0.015625f - mean * mean;
    float rs = rsqrtf(var + 1e-5f);
    float y[16];
#pragma unroll
    for (int j = 0; j < 4; ++j) {
      y[j * 4 + 0] = (xv[j].x - mean) * rs * g4[j].x + b4[j].x;
      y[j * 4 + 1] = (xv[j].y - mean) * rs * g4[j].y + b4[j].y;
      y[j * 4 + 2] = (xv[j].z - mean) * rs * g4[j].z + b4[j].z;
      y[j * 4 + 3] = (xv[j].w - mean) * rs * g4[j].w + b4[j].w;
    }
#pragma unroll
    for (int h = 0; h < 2; ++h) {
      uint4 p;
      p.x = pack2bf(y[h * 8 + 0], y[h * 8 + 1]);
      p.y = pack2bf(y[h * 8 + 2], y[h * 8 + 3]);
      p.z = pack2bf(y[h * 8 + 4], y[h * 8 + 5]);
      p.w = pack2bf(y[h * 8 + 6], y[h * 8 + 7]);
      int c = ql * 2 + h;
      int sc = c ^ (r & 7);
      *(uint4*)&s_xn[r * 64 + sc * 8] = p;
    }
  }
  __syncthreads();

  const int m16 = lane & 15, quad = lane >> 4;
  // xn fragments for this wave's 2 row-tiles (rows (w*2+rt)*16 + m16)
  bf16x8 bf[2][2];
#pragma unroll
  for (int rt = 0; rt < 2; ++rt) {
    int xr = (w * 2 + rt) * 16 + m16;
#pragma unroll
    for (int kt2 = 0; kt2 < 2; ++kt2)
      bf[rt][kt2] = *(const bf16x8*)&s_xn[xr * 64 + (((kt2 * 4 + quad) ^ (xr & 7)) * 8)];
  }

  // ---- k-part: A = xn (m=row), B = Wk (n'=feat) -> D row=xrow(quad*4+rg), col=feat(m16)
  //      lane holds 4 CONSECUTIVE n for fixed feat -> uint2 store into kT[feat][n]
#pragma unroll
  for (int ft = 0; ft < 4; ++ft) {
    bf16x8 wk0 = *(const bf16x8*)&s_w[(ft * 16 + m16) * 64 + quad * 8];
    bf16x8 wk1 = *(const bf16x8*)&s_w[(ft * 16 + m16) * 64 + 32 + quad * 8];
#pragma unroll
    for (int rt = 0; rt < 2; ++rt) {
      floatx4 acc = (floatx4){0.f, 0.f, 0.f, 0.f};
      acc = __builtin_amdgcn_mfma_f32_16x16x32_bf16(bf[rt][0], wk0, acc, 0, 0, 0);
      acc = __builtin_amdgcn_mfma_f32_16x16x32_bf16(bf[rt][1], wk1, acc, 0, 0, 0);
      int n_l = nbase + (w * 2 + rt) * 16 + quad * 4;
      size_t off = ((size_t)bb * 64 + ft * 16 + m16) * N_ + n_l;
      uint2 p;
      p.x = pack2bf(acc[0], acc[1]);
      p.y = pack2bf(acc[2], acc[3]);
      *(uint2*)&kt[off] = p;
    }
  }

  // ---- v-part: A = Wv (m=feat), B = xn (n'=xrow) -> D row=feat(quad*4+rg), col=xrow(m16)
#pragma unroll
  for (int mt = 0; mt < 4; ++mt) {
    bf16x8 wv0 = *(const bf16x8*)&s_w[(64 + mt * 16 + m16) * 64 + quad * 8];
    bf16x8 wv1 = *(const bf16x8*)&s_w[(64 + mt * 16 + m16) * 64 + 32 + quad * 8];
#pragma unroll
    for (int nt = 0; nt < 2; ++nt) {
      floatx4 acc = (floatx4){0.f, 0.f, 0.f, 0.f};
      acc = __builtin_amdgcn_mfma_f32_16x16x32_bf16(wv0, bf[nt][0], acc, 0, 0, 0);
      acc = __builtin_amdgcn_mfma_f32_16x16x32_bf16(wv1, bf[nt][1], acc, 0, 0, 0);
      int xrow_g = R0 + (w * 2 + nt) * 16 + m16;
      int col = mt * 16 + quad * 4;
      uint2 p;
      p.x = pack2bf(acc[0], acc[1]);
      p.y = pack2bf(acc[2], acc[3]);
      *(uint2*)&vb[(size_t)xrow_g * 64 + col] = p;
    }
  }
}

// ---------------- shared helper: q = LN(slots; ln_slots) @ Wq^T * scale ----------------
__device__ void q_from_slots(const float* s_slot, float* s_tmp,
                             const float* __restrict__ g, const float* __restrict__ bb,
                             const float* __restrict__ Wq, float* __restrict__ qout,
                             int lane, int w)
{
  for (int ss = 0; ss < 2; ++ss) {
    int srow = ss * 4 + w;
    if (srow < 7) {
      float xv = s_slot[srow * 64 + lane];
      float s1 = xv, s2 = xv * xv;
#pragma unroll
      for (int mm = 1; mm < 64; mm <<= 1) {
        s1 += __shfl_xor(s1, mm);
        s2 += __shfl_xor(s2, mm);
      }
      float mean = s1 * 0.015625f;
      float var = s2 * 0.015625f - mean * mean;
      float rs = rsqrtf(var + 1e-5f);
      s_tmp[w * 64 + lane] = (xv - mean) * rs * g[lane] + bb[lane];
    }
    __syncthreads();
    if (srow < 7) {
      float acc = 0.f;
      const float* wr = Wq + lane * 64;
      const float* xr = s_tmp + w * 64;
      for (int d = 0; d < 64; ++d) acc += xr[d] * wr[d];
      qout[srow * 64 + lane] = acc * 0.125f;
    }
    __syncthreads();
  }
}

// ---------------- init ----------------
__global__ __launch_bounds__(256) void init_kernel(
    const float* __restrict__ mu, const float* __restrict__ lsig,
    const float* __restrict__ nslots, const float* __restrict__ nh,
    const float* __restrict__ ln_s_g, const float* __restrict__ ln_s_b,
    const float* __restrict__ Wq,
    float* __restrict__ qbuf, float* __restrict__ Wacc, float* __restrict__ Cacc,
    float* __restrict__ h0b)
{
  __shared__ float s_slot[448];
  __shared__ float s_tmp[256];
  const int b = blockIdx.x, t = threadIdx.x, lane = t & 63, w = t >> 6;
  for (int o = t; o < 448; o += 256) {
    int d = o & 63;
    s_slot[o] = mu[d] + expf(lsig[d]) * nslots[b * 448 + o];
    Wacc[b * 448 + o] = 0.f;
  }
  if (t < 64) h0b[b * 64 + t] = mu[t] + expf(lsig[t]) * nh[b * 64 + t];
  if (t < 8) Cacc[b * 8 + t] = 0.f;
  __syncthreads();
  q_from_slots(s_slot, s_tmp, ln_s_g, ln_s_b, Wq, qbuf + b * 448, lane, w);
}

// ---------------- attention pass ----------------
// grid (32, 32): block = 512 rows of one b; wave = one group of 128 rows.
// phase 1: lane owns n-pair; kT column loads coalesced; softmax fully in-register.
// phase 2: lane = (r-quarter lane&3, d-quad lane>>2); accs[7][4]; 2-level shuffle reduce.
__global__ __launch_bounds__(256) void attn_kernel(
    const unsigned short* __restrict__ kt, const unsigned short* __restrict__ vb,
    const float* __restrict__ qbuf,
    float* __restrict__ Wacc, float* __restrict__ Cacc)
{
  __shared__ __align__(16) float s_qt[64 * 8];     // q transposed [d][s], pad to 8
  __shared__ __align__(16) float s_attn[4][7 * 132]; // per-wave [s][n_local], pad 132
  __shared__ __align__(16) float s_red[4][448];
  __shared__ float s_cred[4][8];

  const int b = blockIdx.y;
  const int t = threadIdx.x, lane = t & 63, w = t >> 6;

  for (int i = t; i < 448; i += 256) {
    int s = i >> 6, d = i & 63;
    s_qt[d * 8 + s] = qbuf[b * 448 + i];
  }
  if (t < 64) s_qt[t * 8 + 7] = 0.f;
  __syncthreads();

  const int n0 = blockIdx.x * 512 + w * 128;  // within b

  // ---- phase 1: logits + softmax, lane owns n = n0+2*lane, n0+2*lane+1 ----
  float lg[2][7];
#pragma unroll
  for (int j = 0; j < 2; ++j)
#pragma unroll
    for (int s = 0; s < 7; ++s) lg[j][s] = 0.f;

  const unsigned short* ktb = kt + (size_t)b * 64 * N_ + n0 + 2 * lane;
#pragma unroll 16
  for (int d = 0; d < 64; ++d) {
    unsigned int kk = *(const unsigned int*)(ktb + (size_t)d * N_);
    float k0 = __uint_as_float(kk << 16);
    float k1 = __uint_as_float(kk & 0xffff0000u);
    float4 qa = *(const float4*)&s_qt[d * 8];
    float4 qb = *(const float4*)&s_qt[d * 8 + 4];
    lg[0][0] += k0 * qa.x; lg[0][1] += k0 * qa.y; lg[0][2] += k0 * qa.z; lg[0][3] += k0 * qa.w;
    lg[0][4] += k0 * qb.x; lg[0][5] += k0 * qb.y; lg[0][6] += k0 * qb.z;
    lg[1][0] += k1 * qa.x; lg[1][1] += k1 * qa.y; lg[1][2] += k1 * qa.z; lg[1][3] += k1 * qa.w;
    lg[1][4] += k1 * qb.x; lg[1][5] += k1 * qb.y; lg[1][6] += k1 * qb.z;
  }

  float cloc[7];
#pragma unroll
  for (int s = 0; s < 7; ++s) cloc[s] = 0.f;
  float at[2][7];
#pragma unroll
  for (int j = 0; j < 2; ++j) {
    float mx = lg[j][0];
#pragma unroll
    for (int s = 1; s < 7; ++s) mx = fmaxf(mx, lg[j][s]);
    float sum = 0.f;
#pragma unroll
    for (int s = 0; s < 7; ++s) { at[j][s] = __expf(lg[j][s] - mx); sum += at[j][s]; }
    float inv = 1.f / sum;
#pragma unroll
    for (int s = 0; s < 7; ++s) { at[j][s] = at[j][s] * inv + 1e-8f; }
  }
#pragma unroll
  for (int s = 0; s < 7; ++s) {
    cloc[s] = at[0][s] + at[1][s];
    float2 p = {at[0][s], at[1][s]};
    *(float2*)&s_attn[w][s * 132 + 2 * lane] = p;
  }
  // wave-private LDS round-trip: order ds_write -> ds_read
  asm volatile("s_waitcnt lgkmcnt(0)" ::: "memory");

  // ---- phase 2: lane = (rq = lane&3, dq = lane>>2); v 8B loads; accs[7][4] ----
  const int rq = lane & 3, dq = lane >> 4 ? (lane >> 2) : (lane >> 2);  // dq = lane>>2
  float accs[7][4];
#pragma unroll
  for (int s = 0; s < 7; ++s)
#pragma unroll
    for (int j = 0; j < 4; ++j) accs[s][j] = 0.f;

  const unsigned short* vbb = vb + ((size_t)b * N_ + n0) * 64 + (size_t)dq * 4;
#pragma unroll 8
  for (int rr = 0; rr < 32; ++rr) {
    int r = rr * 4 + rq;
    uint2 vv = *(const uint2*)(vbb + (size_t)r * 64);
    float vf0 = __uint_as_float(vv.x << 16);
    float vf1 = __uint_as_float(vv.x & 0xffff0000u);
    float vf2 = __uint_as_float(vv.y << 16);
    float vf3 = __uint_as_float(vv.y & 0xffff0000u);
#pragma unroll
    for (int s = 0; s < 7; ++s) {
      float av = s_attn[w][s * 132 + r];
      accs[s][0] += av * vf0;
      accs[s][1] += av * vf1;
      accs[s][2] += av * vf2;
      accs[s][3] += av * vf3;
    }
  }
  // reduce over rq (xor 1, 2)
#pragma unroll
  for (int s = 0; s < 7; ++s)
#pragma unroll
    for (int j = 0; j < 4; ++j) {
      float v = accs[s][j];
      v += __shfl_xor(v, 1);
      v += __shfl_xor(v, 2);
      accs[s][j] = v;
    }
  if (rq == 0) {
#pragma unroll
    for (int s = 0; s < 7; ++s)
#pragma unroll
      for (int j = 0; j < 4; ++j)
        s_red[w][s * 64 + dq * 4 + j] = accs[s][j];
  }
  // reduce cloc across all 64 lanes
#pragma unroll
  for (int s = 0; s < 7; ++s) {
    float c = cloc[s];
#pragma unroll
    for (int mm = 1; mm < 64; mm <<= 1) c += __shfl_xor(c, mm);
    cloc[s] = c;
  }
  if (lane == 0) {
#pragma unroll
    for (int s = 0; s < 7; ++s) s_cred[w][s] = cloc[s];
  }
  __syncthreads();
  if (w == 0) {
#pragma unroll
    for (int s = 0; s < 7; ++s) {
      float v = s_red[0][s * 64 + lane] + s_red[1][s * 64 + lane] +
                s_red[2][s * 64 + lane] + s_red[3][s * 64 + lane];
      atomicAdd(&Wacc[b * 448 + s * 64 + lane], v);
    }
    if (lane < 7) {
      float c = s_cred[0][lane] + s_cred[1][lane] + s_cred[2][lane] + s_cred[3][lane];
      atomicAdd(&Cacc[b * 8 + lane], c);
    }
  }
}

// ---------------- slot update ----------------
__global__ __launch_bounds__(256) void slot_update_kernel(
    float* __restrict__ Wacc, float* __restrict__ Cacc,
    const float* __restrict__ h0b,
    const float* __restrict__ w_ih, const float* __restrict__ w_hh,
    const float* __restrict__ b_ih, const float* __restrict__ b_hh,
    const float* __restrict__ ln_m_g, const float* __restrict__ ln_m_b,
    const float* __restrict__ w1, const float* __restrict__ b1,
    const float* __restrict__ w2, const float* __restrict__ b2,
    const float* __restrict__ ln_s_g, const float* __restrict__ ln_s_b,
    const float* __restrict__ Wq,
    float* __restrict__ qbuf, float* __restrict__ out)
{
  const int b = blockIdx.x, t = threadIdx.x, lane = t & 63, w = t >> 6;
  __shared__ float s_upd[448];
  __shared__ float s_gi[1344];
  __shared__ float s_h[64];
  __shared__ float s_gh[192];
  __shared__ float s_slot[448];
  __shared__ float s_tmp[256];

  for (int o = t; o < 448; o += 256) {
    int s = o >> 6;
    s_upd[o] = Wacc[b * 448 + o] / Cacc[b * 8 + s];
  }
  __syncthreads();
  for (int o = t; o < 1344; o += 256) {
    int s = o / 192, j = o - s * 192;
    float acc = b_ih[j];
    const float* wr = w_ih + j * 64;
    const float* ur = s_upd + s * 64;
    for (int d = 0; d < 64; ++d) acc += ur[d] * wr[d];
    s_gi[o] = acc;
  }
  if (t < 64) s_h[t] = h0b[b * 64 + t];
  __syncthreads();
  for (int s = 0; s < 7; ++s) {
    if (t < 192) {
      float acc = b_hh[t];
      const float* wr = w_hh + t * 64;
      for (int d = 0; d < 64; ++d) acc += s_h[d] * wr[d];
      s_gh[t] = acc;
    }
    __syncthreads();
    if (t < 64) {
      float ir = s_gi[s * 192 + t], iz = s_gi[s * 192 + 64 + t], inn = s_gi[s * 192 + 128 + t];
      float hr = s_gh[t], hz = s_gh[64 + t], hn = s_gh[128 + t];
      float r = 1.f / (1.f + expf(-(ir + hr)));
      float z = 1.f / (1.f + expf(-(iz + hz)));
      float n = tanhf(inn + r * hn);
      float hnew = (1.f - z) * n + z * s_h[t];
      s_slot[s * 64 + t] = hnew;
      s_h[t] = hnew;
    }
    __syncthreads();
  }
  float* s_sn = s_gi;
  float* s_hid = s_gi + 448;
  for (int ss = 0; ss < 2; ++ss) {
    int srow = ss * 4 + w;
    if (srow < 7) {
      float xv = s_slot[srow * 64 + lane];
      float s1 = xv, s2 = xv * xv;
#pragma unroll
      for (int mm = 1; mm < 64; mm <<= 1) {
        s1 += __shfl_xor(s1, mm);
        s2 += __shfl_xor(s2, mm);
      }
      float mean = s1 * 0.015625f;
      float var = s2 * 0.015625f - mean * mean;
      float rs = rsqrtf(var + 1e-5f);
      s_sn[srow * 64 + lane] = (xv - mean) * rs * ln_m_g[lane] + ln_m_b[lane];
    }
  }
  __syncthreads();
  for (int o = t; o < 896; o += 256) {
    int s = o >> 7, hh = o & 127;
    float acc = b1[hh];
    const float* wr = w1 + hh * 64;
    const float* xr = s_sn + s * 64;
    for (int d = 0; d < 64; ++d) acc += xr[d] * wr[d];
    s_hid[o] = fmaxf(acc, 0.f);
  }
  __syncthreads();
  for (int o = t; o < 448; o += 256) {
    int s = o >> 6, d = o & 63;
    float acc = b2[d];
    const float* wr = w2 + d * 128;
    const float* hr = s_hid + s * 128;
    for (int h = 0; h < 128; ++h) acc += hr[h] * wr[h];
    float val = s_slot[o] + acc;
    s_slot[o] = val;
    out[b * 448 + o] = val;
  }
  for (int o = t; o < 448; o += 256) Wacc[b * 448 + o] = 0.f;
  if (t < 8) Cacc[b * 8 + t] = 0.f;
  __syncthreads();
  q_from_slots(s_slot, s_tmp, ln_s_g, ln_s_b, Wq, qbuf + b * 448, lane, w);
}

extern "C" void kernel_launch(void* const* d_in, const int* in_sizes, int n_in,
                              void* d_out, int out_size, void* d_ws, size_t ws_size,
                              hipStream_t stream)
{
  (void)in_sizes; (void)n_in; (void)out_size; (void)ws_size;
  const float* x      = (const float*)d_in[0];
  const float* ln_in_g = (const float*)d_in[1];
  const float* ln_in_b = (const float*)d_in[2];
  const float* ln_s_g  = (const float*)d_in[3];
  const float* ln_s_b  = (const float*)d_in[4];
  const float* ln_m_g  = (const float*)d_in[5];
  const float* ln_m_b  = (const float*)d_in[6];
  const float* Wq = (const float*)d_in[7];
  const float* Wk = (const float*)d_in[8];
  const float* Wv = (const float*)d_in[9];
  const float* mu = (const float*)d_in[10];
  const float* lsig = (const float*)d_in[11];
  const float* w_ih = (const float*)d_in[12];
  const float* w_hh = (const float*)d_in[13];
  const float* b_ih = (const float*)d_in[14];
  const float* b_hh = (const float*)d_in[15];
  const float* w1 = (const float*)d_in[16];
  const float* b1 = (const float*)d_in[17];
  const float* w2 = (const float*)d_in[18];
  const float* b2 = (const float*)d_in[19];
  const float* nslots = (const float*)d_in[20];
  const float* nh = (const float*)d_in[21];

  unsigned short* kt = (unsigned short*)d_ws;                 // kT[b][d][n] bf16
  unsigned short* vb = kt + (size_t)B_ * N_ * D_;             // v[b][n][d] bf16
  float* fb = (float*)(vb + (size_t)B_ * N_ * D_);
  float* qbuf = fb;            // 32*448
  float* Wacc = fb + 14336;    // 32*448
  float* Cacc = fb + 28672;    // 32*8
  float* h0b  = fb + 28928;    // 32*64
  float* out = (float*)d_out;

  proj_kernel<<<4096, 256, 0, stream>>>(x, ln_in_g, ln_in_b, Wk, Wv, kt, vb);
  init_kernel<<<32, 256, 0, stream>>>(mu, lsig, nslots, nh, ln_s_g, ln_s_b, Wq,
                                      qbuf, Wacc, Cacc, h0b);
  for (int it = 0; it < 3; ++it) {
    attn_kernel<<<dim3(32, 32), 256, 0, stream>>>(kt, vb, qbuf, Wacc, Cacc);
    slot_update_kernel<<<32, 256, 0, stream>>>(Wacc, Cacc, h0b, w_ih, w_hh, b_ih, b_hh,
                                               ln_m_g, ln_m_b, w1, b1, w2, b2,
                                               ln_s_g, ln_s_b, Wq, qbuf, out);
  }
}

// Round 5
// 423.521 us; speedup vs baseline: 1.4302x; 1.1541x over previous
//
#include <hip/hip_runtime.h>
#include <hip/hip_bf16.h>

// SlotAttention: B=32, N=16384, D=64, S=7, H=128, 3 iterations.
//   proj_kernel : LN(inputs) -> k[b][n][d] + vT[b][d][n] (bf16, MFMA, coalesced LDS epilogue)
//   init_kernel : slots0, h0, zero acc, q0
//   3x { attn_kernel : MFMA logits -> octet-shuffle softmax -> MFMA attn@v, W/C accumulators
//        slot_update : W/C -> GRU (w_hhT in LDS) -> MLP -> slots -> next q }

#define B_ 32
#define N_ 16384
#define D_ 64
#define S_ 7

typedef __bf16 bf16x8 __attribute__((ext_vector_type(8)));
typedef float floatx4 __attribute__((ext_vector_type(4)));

__device__ __forceinline__ unsigned int f2bfu(float f) {
  __hip_bfloat16 h = __float2bfloat16(f);
  return (unsigned int)__builtin_bit_cast(unsigned short, h);
}
__device__ __forceinline__ unsigned int pack2bf(float lo, float hi) {
  return f2bfu(lo) | (f2bfu(hi) << 16);
}

// ---------------- proj: LN + K/V projection ----------------
// k[b][n][d]: attn phase-1 A-frags read 16B/lane directly from global.
// vT[b][d][n]: attn phase-2 B-frags read 16B/lane directly from global.
__global__ __launch_bounds__(256) void proj_kernel(
    const float* __restrict__ x,
    const float* __restrict__ lng, const float* __restrict__ lnb,
    const float* __restrict__ Wk, const float* __restrict__ Wv,
    unsigned short* __restrict__ kb, unsigned short* __restrict__ vt)
{
  __shared__ __align__(16) unsigned char smem[32768];
  unsigned short* s_xn = (unsigned short*)smem;            // [128][64] xor-swizzled
  unsigned short* s_w  = (unsigned short*)(smem + 16384);  // [128][64]
  unsigned short* s_ko = (unsigned short*)smem;            // reuse: k_out [128][72]
  unsigned short* s_vo = (unsigned short*)smem;            // reuse: v_out [64][136]

  const int t = threadIdx.x, lane = t & 63, w = t >> 6;
  const int R0 = blockIdx.x * 128;
  const int bb = R0 >> 14;          // batch (16384 rows per b)
  const int nbase = R0 & (N_ - 1);

  // stage weights: consecutive 16B per thread (conflict-free)
#pragma unroll
  for (int p = 0; p < 4; ++p) {
    int idx = (p * 256 + t) * 8;
    const float* src = (idx < 4096) ? (Wk + idx) : (Wv + idx - 4096);
    float4 a = ((const float4*)src)[0], b = ((const float4*)src)[1];
    uint4 pk;
    pk.x = pack2bf(a.x, a.y); pk.y = pack2bf(a.z, a.w);
    pk.z = pack2bf(b.x, b.y); pk.w = pack2bf(b.z, b.w);
    *(uint4*)&s_w[idx] = pk;
  }

  // LayerNorm: 4 lanes per row, 16 f32 each
  const int ql = t & 3;
  float4 g4[4], b4[4];
#pragma unroll
  for (int j = 0; j < 4; ++j) {
    g4[j] = *(const float4*)&lng[ql * 16 + j * 4];
    b4[j] = *(const float4*)&lnb[ql * 16 + j * 4];
  }
#pragma unroll
  for (int half = 0; half < 2; ++half) {
    int r = half * 64 + (t >> 2);
    const float4* xp = (const float4*)&x[(size_t)(R0 + r) * 64 + ql * 16];
    float4 xv[4];
#pragma unroll
    for (int j = 0; j < 4; ++j) xv[j] = xp[j];
    float s1 = 0.f, s2 = 0.f;
#pragma unroll
    for (int j = 0; j < 4; ++j) {
      s1 += xv[j].x + xv[j].y + xv[j].z + xv[j].w;
      s2 += xv[j].x * xv[j].x + xv[j].y * xv[j].y + xv[j].z * xv[j].z + xv[j].w * xv[j].w;
    }
    s1 += __shfl_xor(s1, 1); s2 += __shfl_xor(s2, 1);
    s1 += __shfl_xor(s1, 2); s2 += __shfl_xor(s2, 2);
    float mean = s1 * 0.015625f;
    float var = s2 * 0.015625f - mean * mean;
    float rs = rsqrtf(var + 1e-5f);
    float y[16];
#pragma unroll
    for (int j = 0; j < 4; ++j) {
      y[j * 4 + 0] = (xv[j].x - mean) * rs * g4[j].x + b4[j].x;
      y[j * 4 + 1] = (xv[j].y - mean) * rs * g4[j].y + b4[j].y;
      y[j * 4 + 2] = (xv[j].z - mean) * rs * g4[j].z + b4[j].z;
      y[j * 4 + 3] = (xv[j].w - mean) * rs * g4[j].w + b4[j].w;
    }
#pragma unroll
    for (int h = 0; h < 2; ++h) {
      uint4 p;
      p.x = pack2bf(y[h * 8 + 0], y[h * 8 + 1]);
      p.y = pack2bf(y[h * 8 + 2], y[h * 8 + 3]);
      p.z = pack2bf(y[h * 8 + 4], y[h * 8 + 5]);
      p.w = pack2bf(y[h * 8 + 6], y[h * 8 + 7]);
      int c = ql * 2 + h;
      int sc = c ^ (r & 7);
      *(uint4*)&s_xn[r * 64 + sc * 8] = p;
    }
  }
  __syncthreads();

  const int m16 = lane & 15, quad = lane >> 4;
  // preload ALL fragments (s_xn/s_w dead afterwards -> reuse for outputs)
  bf16x8 bf[2][2];   // xn: lane m16 = xrow-within-tile, k = quad*8+j (+32)
#pragma unroll
  for (int rt = 0; rt < 2; ++rt) {
    int xr = (w * 2 + rt) * 16 + m16;
#pragma unroll
    for (int kk = 0; kk < 2; ++kk)
      bf[rt][kk] = *(const bf16x8*)&s_xn[xr * 64 + (((kk * 4 + quad) ^ (xr & 7)) * 8)];
  }
  bf16x8 wkf[4][2], wvf[4][2];
#pragma unroll
  for (int ft = 0; ft < 4; ++ft)
#pragma unroll
    for (int kk = 0; kk < 2; ++kk) {
      wkf[ft][kk] = *(const bf16x8*)&s_w[(ft * 16 + m16) * 64 + kk * 32 + quad * 8];
      wvf[ft][kk] = *(const bf16x8*)&s_w[(64 + ft * 16 + m16) * 64 + kk * 32 + quad * 8];
    }
  __syncthreads();

  // k-part: A=Wk (m=d), B=xn (n'=n). D: d = ft*16+quad*4+rg, n = tile_rt*16+m16
#pragma unroll
  for (int ft = 0; ft < 4; ++ft)
#pragma unroll
    for (int rt = 0; rt < 2; ++rt) {
      floatx4 acc = (floatx4){0.f, 0.f, 0.f, 0.f};
      acc = __builtin_amdgcn_mfma_f32_16x16x32_bf16(wkf[ft][0], bf[rt][0], acc, 0, 0, 0);
      acc = __builtin_amdgcn_mfma_f32_16x16x32_bf16(wkf[ft][1], bf[rt][1], acc, 0, 0, 0);
      int n_l = (w * 2 + rt) * 16 + m16;
      uint2 p;
      p.x = pack2bf(acc[0], acc[1]);
      p.y = pack2bf(acc[2], acc[3]);
      *(uint2*)&s_ko[n_l * 72 + ft * 16 + quad * 4] = p;
    }
  __syncthreads();
  // coalesced k store: linear [n][d]
#pragma unroll
  for (int p = 0; p < 4; ++p) {
    int ii = (p * 256 + t) * 8;
    int n_l = ii >> 6, dl = ii & 63;
    uint4 v4 = *(const uint4*)&s_ko[n_l * 72 + dl];
    *(uint4*)&kb[(size_t)(R0 + n_l) * 64 + dl] = v4;
  }
  __syncthreads();

  // v-part: A=xn (m=n), B=Wv (n'=d). D: n = tile_rt*16+quad*4+rg, d = ft*16+m16
#pragma unroll
  for (int ft = 0; ft < 4; ++ft)
#pragma unroll
    for (int rt = 0; rt < 2; ++rt) {
      floatx4 acc = (floatx4){0.f, 0.f, 0.f, 0.f};
      acc = __builtin_amdgcn_mfma_f32_16x16x32_bf16(bf[rt][0], wvf[ft][0], acc, 0, 0, 0);
      acc = __builtin_amdgcn_mfma_f32_16x16x32_bf16(bf[rt][1], wvf[ft][1], acc, 0, 0, 0);
      int n_l = (w * 2 + rt) * 16 + quad * 4;
      int d0 = ft * 16 + m16;
      uint2 p;
      p.x = pack2bf(acc[0], acc[1]);
      p.y = pack2bf(acc[2], acc[3]);
      *(uint2*)&s_vo[d0 * 136 + n_l] = p;
    }
  __syncthreads();
  // coalesced vT store: rows d, 128 n per row
#pragma unroll
  for (int p = 0; p < 4; ++p) {
    int ii = (p * 256 + t) * 8;
    int d0 = ii >> 7, nl = ii & 127;
    uint4 v4 = *(const uint4*)&s_vo[d0 * 136 + nl];
    *(uint4*)&vt[((size_t)bb * 64 + d0) * N_ + nbase + nl] = v4;
  }
}

// ---------------- shared helper: q = LN(slots; ln_slots) @ Wq^T * scale ----------------
__device__ void q_from_slots(const float* s_slot, float* s_tmp,
                             const float* __restrict__ g, const float* __restrict__ bb,
                             const float* __restrict__ Wq, float* __restrict__ qout,
                             int lane, int w)
{
  for (int ss = 0; ss < 2; ++ss) {
    int srow = ss * 4 + w;
    if (srow < 7) {
      float xv = s_slot[srow * 64 + lane];
      float s1 = xv, s2 = xv * xv;
#pragma unroll
      for (int mm = 1; mm < 64; mm <<= 1) {
        s1 += __shfl_xor(s1, mm);
        s2 += __shfl_xor(s2, mm);
      }
      float mean = s1 * 0.015625f;
      float var = s2 * 0.015625f - mean * mean;
      float rs = rsqrtf(var + 1e-5f);
      s_tmp[w * 64 + lane] = (xv - mean) * rs * g[lane] + bb[lane];
    }
    __syncthreads();
    if (srow < 7) {
      float acc = 0.f;
      const float4* wr = (const float4*)(Wq + lane * 64);
      const float4* xr = (const float4*)(s_tmp + w * 64);
#pragma unroll
      for (int i = 0; i < 16; ++i) {
        float4 a = wr[i], xx = xr[i];
        acc += a.x * xx.x + a.y * xx.y + a.z * xx.z + a.w * xx.w;
      }
      qout[srow * 64 + lane] = acc * 0.125f;
    }
    __syncthreads();
  }
}

// ---------------- init ----------------
__global__ __launch_bounds__(256) void init_kernel(
    const float* __restrict__ mu, const float* __restrict__ lsig,
    const float* __restrict__ nslots, const float* __restrict__ nh,
    const float* __restrict__ ln_s_g, const float* __restrict__ ln_s_b,
    const float* __restrict__ Wq,
    float* __restrict__ qbuf, float* __restrict__ Wacc, float* __restrict__ Cacc,
    float* __restrict__ h0b)
{
  __shared__ float s_slot[448];
  __shared__ float s_tmp[256];
  const int b = blockIdx.x, t = threadIdx.x, lane = t & 63, w = t >> 6;
  for (int o = t; o < 448; o += 256) {
    int d = o & 63;
    s_slot[o] = mu[d] + expf(lsig[d]) * nslots[b * 448 + o];
    Wacc[b * 448 + o] = 0.f;
  }
  if (t < 64) h0b[b * 64 + t] = mu[t] + expf(lsig[t]) * nh[b * 64 + t];
  if (t < 8) Cacc[b * 8 + t] = 0.f;
  __syncthreads();
  q_from_slots(s_slot, s_tmp, ln_s_g, ln_s_b, Wq, qbuf + b * 448, lane, w);
}

// ---------------- attention pass (MFMA both phases) ----------------
// grid (32,32): block = 512 n of one b; wave = 128 n.
// phase 1: logits[n][s] = mfma(k_frag_global, q_frag);  softmax across s via octet shuffles.
// phase 2: upd[s][d]   = mfma(attn_bf16_frag, vT_frag_global), accumulate over n-chunks.
__global__ __launch_bounds__(256) void attn_kernel(
    const unsigned short* __restrict__ kb, const unsigned short* __restrict__ vt,
    const float* __restrict__ qbuf,
    float* __restrict__ Wacc, float* __restrict__ Cacc)
{
  __shared__ __align__(16) unsigned short s_qb[16 * 64];       // q bf16 [s][d], rows 7..15 = 0
  __shared__ __align__(16) unsigned short s_at[4][16 * 136];   // per-wave attn bf16 [s][n], rows 7..15 junk
  __shared__ __align__(16) float s_red[4][448];
  __shared__ float s_cred[4][8];

  const int b = blockIdx.y;
  const int t = threadIdx.x, lane = t & 63, w = t >> 6;
  const int m16 = lane & 15, quad = lane >> 4;

  // stage q as bf16 B-frag source (rows >= 7 zero)
  {
    int i0 = t * 4;
    int s = i0 >> 6, d0 = i0 & 63;
    float f0 = 0.f, f1 = 0.f, f2 = 0.f, f3 = 0.f;
    if (s < 7) {
      const float* qp = qbuf + b * 448 + s * 64 + d0;
      f0 = qp[0]; f1 = qp[1]; f2 = qp[2]; f3 = qp[3];
    }
    uint2 p;
    p.x = pack2bf(f0, f1);
    p.y = pack2bf(f2, f3);
    *(uint2*)&s_qb[i0] = p;
  }
  __syncthreads();

  bf16x8 bq0 = *(const bf16x8*)&s_qb[m16 * 64 + quad * 8];
  bf16x8 bq1 = *(const bf16x8*)&s_qb[m16 * 64 + 32 + quad * 8];

  const int n0w = blockIdx.x * 512 + w * 128;
  const unsigned short* kbA = kb + ((size_t)b * N_ + n0w) * 64;

  // ---- phase 1: 8 n-tiles of 16 ----
  float cl = 0.f;
#pragma unroll
  for (int nt = 0; nt < 8; ++nt) {
    bf16x8 a0 = *(const bf16x8*)&kbA[(size_t)(nt * 16 + m16) * 64 + quad * 8];
    bf16x8 a1 = *(const bf16x8*)&kbA[(size_t)(nt * 16 + m16) * 64 + 32 + quad * 8];
    floatx4 c = (floatx4){0.f, 0.f, 0.f, 0.f};
    c = __builtin_amdgcn_mfma_f32_16x16x32_bf16(a0, bq0, c, 0, 0, 0);
    c = __builtin_amdgcn_mfma_f32_16x16x32_bf16(a1, bq1, c, 0, 0, 0);
    // lane holds logits[n = nt*16 + quad*4 + rg][s = m16]; softmax over s (octet shuffles)
    float atv[4];
#pragma unroll
    for (int rg = 0; rg < 4; ++rg) {
      float xx = (m16 < 7) ? c[rg] : -1e30f;
      float mx = xx;
      mx = fmaxf(mx, __shfl_xor(mx, 1));
      mx = fmaxf(mx, __shfl_xor(mx, 2));
      mx = fmaxf(mx, __shfl_xor(mx, 4));
      float e = __expf(xx - mx);
      float sm = e;
      sm += __shfl_xor(sm, 1);
      sm += __shfl_xor(sm, 2);
      sm += __shfl_xor(sm, 4);
      float a = e / sm + 1e-8f;
      atv[rg] = a;
      cl += a;
    }
    if (m16 < 7) {
      uint2 p;
      p.x = pack2bf(atv[0], atv[1]);
      p.y = pack2bf(atv[2], atv[3]);
      *(uint2*)&s_at[w][m16 * 136 + nt * 16 + quad * 4] = p;
    }
  }
  // wave-private LDS: ensure writes visible before frag reads
  asm volatile("s_waitcnt lgkmcnt(0)" ::: "memory");

  // ---- phase 2: 4 n-chunks of 32 x 4 d-tiles ----
  floatx4 acc[4];
#pragma unroll
  for (int dt = 0; dt < 4; ++dt) acc[dt] = (floatx4){0.f, 0.f, 0.f, 0.f};
  const unsigned short* vtB = vt + (size_t)b * 64 * N_ + n0w;
#pragma unroll
  for (int ch = 0; ch < 4; ++ch) {
    bf16x8 af = *(const bf16x8*)&s_at[w][m16 * 136 + ch * 32 + quad * 8];
#pragma unroll
    for (int dt = 0; dt < 4; ++dt) {
      bf16x8 bv = *(const bf16x8*)&vtB[(size_t)(dt * 16 + m16) * N_ + ch * 32 + quad * 8];
      acc[dt] = __builtin_amdgcn_mfma_f32_16x16x32_bf16(af, bv, acc[dt], 0, 0, 0);
    }
  }
  // D: lane holds upd[s = quad*4+rg][d = dt*16+m16]; valid s<7 (quad<2)
  if (quad < 2) {
#pragma unroll
    for (int dt = 0; dt < 4; ++dt)
#pragma unroll
      for (int rg = 0; rg < 4; ++rg) {
        int s = quad * 4 + rg;
        if (s < 7) s_red[w][s * 64 + dt * 16 + m16] = acc[dt][rg];
      }
  }
  // cloc: lane's partial for s=m16; combine quads
  cl += __shfl_xor(cl, 16);
  cl += __shfl_xor(cl, 32);
  if (m16 < 7 && quad == 0) s_cred[w][m16] = cl;
  __syncthreads();
  if (w == 0) {
#pragma unroll
    for (int s = 0; s < 7; ++s) {
      float v = s_red[0][s * 64 + lane] + s_red[1][s * 64 + lane] +
                s_red[2][s * 64 + lane] + s_red[3][s * 64 + lane];
      atomicAdd(&Wacc[b * 448 + s * 64 + lane], v);
    }
    if (lane < 7) {
      float c = s_cred[0][lane] + s_cred[1][lane] + s_cred[2][lane] + s_cred[3][lane];
      atomicAdd(&Cacc[b * 8 + lane], c);
    }
  }
}

// ---------------- slot update ----------------
__global__ __launch_bounds__(256) void slot_update_kernel(
    float* __restrict__ Wacc, float* __restrict__ Cacc,
    const float* __restrict__ h0b,
    const float* __restrict__ w_ih, const float* __restrict__ w_hh,
    const float* __restrict__ b_ih, const float* __restrict__ b_hh,
    const float* __restrict__ ln_m_g, const float* __restrict__ ln_m_b,
    const float* __restrict__ w1, const float* __restrict__ b1,
    const float* __restrict__ w2, const float* __restrict__ b2,
    const float* __restrict__ ln_s_g, const float* __restrict__ ln_s_b,
    const float* __restrict__ Wq,
    float* __restrict__ qbuf, float* __restrict__ out)
{
  const int b = blockIdx.x, t = threadIdx.x, lane = t & 63, w = t >> 6;
  __shared__ float s_whhT[64 * 201];   // w_hh transposed [d][j], pad 201 (conflict-free)
  __shared__ float s_upd[448];
  __shared__ float s_gi[1344];
  __shared__ float s_h[64];
  __shared__ float s_gh[192];
  __shared__ float s_slot[448];
  __shared__ float s_tmp[256];

  // stage w_hhT (coalesced global reads)
  for (int i = t; i < 12288; i += 256) {
    int j = i >> 6, d = i & 63;
    s_whhT[d * 201 + j] = w_hh[i];
  }
  for (int o = t; o < 448; o += 256) {
    int s = o >> 6;
    s_upd[o] = Wacc[b * 448 + o] / Cacc[b * 8 + s];
  }
  if (t < 64) s_h[t] = h0b[b * 64 + t];
  __syncthreads();
  // gi = updates @ w_ih^T + b_ih (float4)
  for (int o = t; o < 1344; o += 256) {
    int s = o / 192, j = o - s * 192;
    float acc = b_ih[j];
    const float4* wr = (const float4*)(w_ih + j * 64);
    const float4* ur = (const float4*)(s_upd + s * 64);
#pragma unroll
    for (int i = 0; i < 16; ++i) {
      float4 a = wr[i], u = ur[i];
      acc += a.x * u.x + a.y * u.y + a.z * u.z + a.w * u.w;
    }
    s_gi[o] = acc;
  }
  __syncthreads();
  // GRU over slots (gate order r,z,n)
  for (int s = 0; s < 7; ++s) {
    if (t < 192) {
      float acc = b_hh[t];
#pragma unroll 16
      for (int d = 0; d < 64; ++d) acc += s_h[d] * s_whhT[d * 201 + t];
      s_gh[t] = acc;
    }
    __syncthreads();
    if (t < 64) {
      float ir = s_gi[s * 192 + t], iz = s_gi[s * 192 + 64 + t], inn = s_gi[s * 192 + 128 + t];
      float hr = s_gh[t], hz = s_gh[64 + t], hn = s_gh[128 + t];
      float r = 1.f / (1.f + expf(-(ir + hr)));
      float z = 1.f / (1.f + expf(-(iz + hz)));
      float n = tanhf(inn + r * hn);
      float hnew = (1.f - z) * n + z * s_h[t];
      s_slot[s * 64 + t] = hnew;
      s_h[t] = hnew;
    }
    __syncthreads();
  }
  // MLP with residual
  float* s_sn = s_gi;
  float* s_hid = s_gi + 448;
  for (int ss = 0; ss < 2; ++ss) {
    int srow = ss * 4 + w;
    if (srow < 7) {
      float xv = s_slot[srow * 64 + lane];
      float s1 = xv, s2 = xv * xv;
#pragma unroll
      for (int mm = 1; mm < 64; mm <<= 1) {
        s1 += __shfl_xor(s1, mm);
        s2 += __shfl_xor(s2, mm);
      }
      float mean = s1 * 0.015625f;
      float var = s2 * 0.015625f - mean * mean;
      float rs = rsqrtf(var + 1e-5f);
      s_sn[srow * 64 + lane] = (xv - mean) * rs * ln_m_g[lane] + ln_m_b[lane];
    }
  }
  __syncthreads();
  for (int o = t; o < 896; o += 256) {
    int s = o >> 7, hh = o & 127;
    float acc = b1[hh];
    const float4* wr = (const float4*)(w1 + hh * 64);
    const float4* xr = (const float4*)(s_sn + s * 64);
#pragma unroll
    for (int i = 0; i < 16; ++i) {
      float4 a = wr[i], xx = xr[i];
      acc += a.x * xx.x + a.y * xx.y + a.z * xx.z + a.w * xx.w;
    }
    s_hid[o] = fmaxf(acc, 0.f);
  }
  __syncthreads();
  for (int o = t; o < 448; o += 256) {
    int s = o >> 6, d = o & 63;
    float acc = b2[d];
    const float4* wr = (const float4*)(w2 + d * 128);
    const float4* hr = (const float4*)(s_hid + s * 128);
#pragma unroll
    for (int i = 0; i < 32; ++i) {
      float4 a = wr[i], hv = hr[i];
      acc += a.x * hv.x + a.y * hv.y + a.z * hv.z + a.w * hv.w;
    }
    float val = s_slot[o] + acc;
    s_slot[o] = val;
    out[b * 448 + o] = val;
  }
  for (int o = t; o < 448; o += 256) Wacc[b * 448 + o] = 0.f;
  if (t < 8) Cacc[b * 8 + t] = 0.f;
  __syncthreads();
  q_from_slots(s_slot, s_tmp, ln_s_g, ln_s_b, Wq, qbuf + b * 448, lane, w);
}

extern "C" void kernel_launch(void* const* d_in, const int* in_sizes, int n_in,
                              void* d_out, int out_size, void* d_ws, size_t ws_size,
                              hipStream_t stream)
{
  (void)in_sizes; (void)n_in; (void)out_size; (void)ws_size;
  const float* x      = (const float*)d_in[0];
  const float* ln_in_g = (const float*)d_in[1];
  const float* ln_in_b = (const float*)d_in[2];
  const float* ln_s_g  = (const float*)d_in[3];
  const float* ln_s_b  = (const float*)d_in[4];
  const float* ln_m_g  = (const float*)d_in[5];
  const float* ln_m_b  = (const float*)d_in[6];
  const float* Wq = (const float*)d_in[7];
  const float* Wk = (const float*)d_in[8];
  const float* Wv = (const float*)d_in[9];
  const float* mu = (const float*)d_in[10];
  const float* lsig = (const float*)d_in[11];
  const float* w_ih = (const float*)d_in[12];
  const float* w_hh = (const float*)d_in[13];
  const float* b_ih = (const float*)d_in[14];
  const float* b_hh = (const float*)d_in[15];
  const float* w1 = (const float*)d_in[16];
  const float* b1 = (const float*)d_in[17];
  const float* w2 = (const float*)d_in[18];
  const float* b2 = (const float*)d_in[19];
  const float* nslots = (const float*)d_in[20];
  const float* nh = (const float*)d_in[21];

  unsigned short* kb = (unsigned short*)d_ws;                 // k[b][n][d] bf16
  unsigned short* vt = kb + (size_t)B_ * N_ * D_;             // vT[b][d][n] bf16
  float* fb = (float*)(vt + (size_t)B_ * N_ * D_);
  float* qbuf = fb;            // 32*448
  float* Wacc = fb + 14336;    // 32*448
  float* Cacc = fb + 28672;    // 32*8
  float* h0b  = fb + 28928;    // 32*64
  float* out = (float*)d_out;

  proj_kernel<<<4096, 256, 0, stream>>>(x, ln_in_g, ln_in_b, Wk, Wv, kb, vt);
  init_kernel<<<32, 256, 0, stream>>>(mu, lsig, nslots, nh, ln_s_g, ln_s_b, Wq,
                                      qbuf, Wacc, Cacc, h0b);
  for (int it = 0; it < 3; ++it) {
    attn_kernel<<<dim3(32, 32), 256, 0, stream>>>(kb, vt, qbuf, Wacc, Cacc);
    slot_update_kernel<<<32, 256, 0, stream>>>(Wacc, Cacc, h0b, w_ih, w_hh, b_ih, b_hh,
                                               ln_m_g, ln_m_b, w1, b1, w2, b2,
                                               ln_s_g, ln_s_b, Wq, qbuf, out);
  }
}